// Round 10
// baseline (493.292 us; speedup 1.0000x reference)
//
#include <hip/hip_runtime.h>
#include <math.h>

constexpr int BLK = 256;
constexpr int NBLKA = 256;     // phase-A blocks for edge bucketing
constexpr int GCAP = 2048;     // gather grid cap: 8 blocks/CU fills 32 waves/CU

static inline int cdiv(long a, long b) { return (int)((a + b - 1) / b); }

typedef __attribute__((ext_vector_type(8))) short short8;
typedef __attribute__((ext_vector_type(4))) float floatx4;

// ---------------- bf16 helpers (RNE) -----------------------------------------
__device__ __forceinline__ unsigned short f2bf(float f) {
    unsigned u = __float_as_uint(f);
    unsigned r = u + 0x7fffu + ((u >> 16) & 1u);
    return (unsigned short)(r >> 16);
}
__device__ __forceinline__ float bf2f(unsigned short s) {
    return __uint_as_float(((unsigned)s) << 16);
}

// ============== CSR build via 2-phase bucket sort (NO global atomics) ========
// Bucket b covers nodes [b*256, b*256+256). histg layout: [z*nbkt + b].

__global__ void histA_k(const int* __restrict__ dst, int* __restrict__ histg,
                        int E, int nbkt, int chunk) {
    __shared__ int h[256];
    int tid = threadIdx.x, z = blockIdx.x;
    h[tid] = 0;
    __syncthreads();
    int e0 = z * chunk, e1 = min(E, e0 + chunk);
    for (int e = e0 + tid; e < e1; e += BLK) atomicAdd(&h[dst[e] >> 8], 1);
    __syncthreads();
    if (tid < nbkt) histg[z * nbkt + tid] = h[tid];
}

__global__ void bucket_scan_k(const int* __restrict__ histg, int* __restrict__ bucket_base,
                              int nbkt, int E, int* __restrict__ gs, int* __restrict__ ge,
                              int G, float* __restrict__ bnstats) {
    __shared__ int s[BLK];
    int t = threadIdx.x;
    int v = 0;
    if (t < nbkt)
        for (int z = 0; z < NBLKA; ++z) v += histg[z * nbkt + t];
    s[t] = v;
    __syncthreads();
    for (int o = 1; o < BLK; o <<= 1) {
        int tv = (t >= o) ? s[t - o] : 0;
        __syncthreads();
        s[t] += tv;
        __syncthreads();
    }
    if (t < nbkt) bucket_base[t] = s[t] - v;
    if (t == 0) bucket_base[nbkt] = E;
    for (int i = t; i < G; i += BLK) { gs[i] = 0x7fffffff; ge[i] = -1; }
    for (int i = t; i < 1024; i += BLK) bnstats[i] = 0.f;   // 4 layers x 256
}

__global__ void blk_scan_k(int* __restrict__ histg, const int* __restrict__ bucket_base,
                           int nbkt) {
    __shared__ int s[BLK];
    int t = threadIdx.x, b = blockIdx.x;
    int v = histg[t * nbkt + b];
    s[t] = v;
    __syncthreads();
    for (int o = 1; o < BLK; o <<= 1) {
        int tv = (t >= o) ? s[t - o] : 0;
        __syncthreads();
        s[t] += tv;
        __syncthreads();
    }
    histg[t * nbkt + b] = bucket_base[b] + s[t] - v;
}

__global__ void scatterA_k(const int* __restrict__ src, const int* __restrict__ dst,
                           const int* __restrict__ histg, unsigned* __restrict__ ebkt,
                           int E, int nbkt, int chunk) {
    __shared__ int cur[256];
    int tid = threadIdx.x, z = blockIdx.x;
    if (tid < nbkt) cur[tid] = histg[z * nbkt + tid];
    __syncthreads();
    int e0 = z * chunk, e1 = min(E, e0 + chunk);
    for (int e = e0 + tid; e < e1; e += BLK) {
        int d = dst[e];
        int b = d >> 8;
        int pos = atomicAdd(&cur[b], 1);
        ebkt[pos] = ((unsigned)(d & 255) << 16) | (unsigned)src[e];
    }
}

// B: per-bucket CSR finalize (degrees->scan->self-loop->fill) + graph ranges.
__global__ void csrB_k(const unsigned* __restrict__ ebkt, const int* __restrict__ bucket_base,
                       int* __restrict__ off, unsigned short* __restrict__ csr,
                       const int* __restrict__ batch, int* __restrict__ gs,
                       int* __restrict__ ge, int N, int E, int nbkt) {
    __shared__ int dg[256];
    __shared__ int sc[256];
    int t = threadIdx.x, b = blockIdx.x;
    int n0 = b << 8;
    int cnt = min(256, N - n0);
    dg[t] = (t < cnt) ? 1 : 0;                     // self-loop
    __syncthreads();
    int e0 = bucket_base[b], e1 = bucket_base[b + 1];
    for (int e = e0 + t; e < e1; e += BLK) atomicAdd(&dg[ebkt[e] >> 16], 1);
    __syncthreads();
    int d = dg[t];
    sc[t] = d;
    __syncthreads();
    for (int o = 1; o < BLK; o <<= 1) {
        int tv = (t >= o) ? sc[t - o] : 0;
        __syncthreads();
        sc[t] += tv;
        __syncthreads();
    }
    int loff = sc[t] - d;                          // exclusive
    int csrbase = e0 + n0;                         // n0 self-loops precede bucket
    if (t < cnt) {
        off[n0 + t] = csrbase + loff;
        csr[csrbase + loff] = (unsigned short)(n0 + t);   // self-loop slot
        dg[t] = loff + 1;                          // cursor
    }
    if (b == nbkt - 1 && t == 0) off[N] = E + N;
    // graph ranges (batch sorted): boundary detection, this grid covers N.
    int n = n0 + t;
    if (n < N) {
        int bb = batch[n];
        if (n == 0) gs[bb] = 0;
        else {
            int pb = batch[n - 1];
            if (pb != bb) { gs[bb] = n; ge[pb] = n - 1; }
        }
        if (n == N - 1) ge[bb] = N - 1;
    }
    __syncthreads();
    for (int e = e0 + t; e < e1; e += BLK) {
        unsigned w = ebkt[e];
        int pos = atomicAdd(&dg[w >> 16], 1);
        csr[csrbase + pos] = (unsigned short)(w & 0xffff);
    }
}

// ---------------- self-contained MFMA GEMM (prep fused in prologue) -----------
template <int K, int NOUT, bool AFP32, bool HASBN>
__launch_bounds__(256)
__global__ void gemm_fused(const void* __restrict__ av, const float* __restrict__ W,
                           const float* __restrict__ a_s, const float* __restrict__ a_d,
                           const float* __restrict__ bnst, const float* __restrict__ g_prev,
                           const float* __restrict__ be_prev, float invN,
                           unsigned short* __restrict__ hb,
                           float* __restrict__ asrc, float* __restrict__ adst, int N) {
    constexpr int KF = K / 32;
    __shared__ float s_sca[K], s_scc[K], s_rs[K], s_rd[K], s_bd[2];
    int tid = threadIdx.x;
    if (tid < K) {
        float a = 1.f, c = 0.f;
        if (HASBN) {
            float mu = bnst[tid] * invN;
            float var = bnst[128 + tid] * invN - mu * mu;
            a = g_prev[tid] * rsqrtf(var + 1e-5f);
            c = be_prev[tid] - mu * a;
        }
        s_sca[tid] = a; s_scc[tid] = c;
    }
    __syncthreads();
    const bool dots = (blockIdx.y == 0);
    if (dots) {                             // block-uniform branch: syncs legal
        if (tid < K) {
            const float* wr = W + (long)tid * NOUT;
            float rs = 0.f, rd = 0.f;
            for (int f = 0; f < NOUT; ++f) {
                float w = wr[f];
                rs += w * a_s[f];
                rd += w * a_d[f];
            }
            s_rs[tid] = rs; s_rd[tid] = rd;
        }
        __syncthreads();
        if (tid < 2) {
            const float* r = tid ? s_rd : s_rs;
            float b = 0.f;
            for (int k = 0; k < K; ++k) b += s_scc[k] * r[k];
            s_bd[tid] = b;
        }
        __syncthreads();
    }

    int wave = tid >> 6;
    int lane = tid & 63;
    int quad = lane >> 4;
    int r16 = lane & 15;
    int col = blockIdx.y * 16 + r16;

    // ---- B fragment (BN-scaled inline) + bias[col] partial ----
    short8 bfr[KF];
    float biasp = 0.f;
#pragma unroll
    for (int kk = 0; kk < KF; ++kk) {
        short8 b;
#pragma unroll
        for (int j = 0; j < 8; ++j) {
            int k = kk * 32 + quad * 8 + j;
            float w = W[(long)k * NOUT + col];
            b[j] = (short)f2bf(s_sca[k] * w);
            biasp += s_scc[k] * w;
        }
        bfr[kk] = b;
    }
    biasp += __shfl_xor(biasp, 16, 64);
    biasp += __shfl_xor(biasp, 32, 64);

    int blockbase = blockIdx.x * 128;
#pragma unroll
    for (int rt = 0; rt < 2; ++rt) {
        int tilebase = blockbase + wave * 32 + rt * 16;
        if (tilebase >= N) break;                       // wave-uniform
        int arow = min(tilebase + r16, N - 1);
        short8 afr[KF];
        if (AFP32) {
            const float* xr = (const float*)av + (long)arow * K;
#pragma unroll
            for (int kk = 0; kk < KF; ++kk) {
                float4 x0 = *(const float4*)(xr + kk * 32 + quad * 8);
                float4 x1 = *(const float4*)(xr + kk * 32 + quad * 8 + 4);
                short8 a;
                a[0] = (short)f2bf(x0.x); a[1] = (short)f2bf(x0.y);
                a[2] = (short)f2bf(x0.z); a[3] = (short)f2bf(x0.w);
                a[4] = (short)f2bf(x1.x); a[5] = (short)f2bf(x1.y);
                a[6] = (short)f2bf(x1.z); a[7] = (short)f2bf(x1.w);
                afr[kk] = a;
            }
        } else {
            const unsigned short* hr = (const unsigned short*)av + (long)arow * K;
#pragma unroll
            for (int kk = 0; kk < KF; ++kk)
                afr[kk] = *(const short8*)(hr + kk * 32 + quad * 8);
        }
        floatx4 acc = {0.f, 0.f, 0.f, 0.f};
#pragma unroll
        for (int kk = 0; kk < KF; ++kk)
            acc = __builtin_amdgcn_mfma_f32_16x16x32_bf16(afr[kk], bfr[kk], acc, 0, 0, 0);
#pragma unroll
        for (int rr = 0; rr < 4; ++rr) {
            int srow = tilebase + quad * 4 + rr;
            if (srow < N) hb[(long)srow * NOUT + col] = f2bf(acc[rr] + biasp);
        }
        if (dots) {
            float ds = 0.f, dd = 0.f;
#pragma unroll
            for (int kk = 0; kk < KF; ++kk) {
                int kb = kk * 32 + quad * 8;
#pragma unroll
                for (int j = 0; j < 8; ++j) {
                    int k = kb + j;
                    float a = bf2f((unsigned short)afr[kk][j]) * s_sca[k];
                    ds += a * s_rs[k];
                    dd += a * s_rd[k];
                }
            }
            ds += __shfl_xor(ds, 16, 64); ds += __shfl_xor(ds, 32, 64);
            dd += __shfl_xor(dd, 16, 64); dd += __shfl_xor(dd, 32, 64);
            int drow = tilebase + r16;
            if (quad == 0 && drow < N) {
                asrc[drow] = ds + s_bd[0];
                adst[drow] = dd + s_bd[1];
            }
        }
    }
}

// ---------------- fused softmax + gather + bias + leaky + BN STATS -----------
// Grid-stride, grid = min(natural, GCAP=2048). Per-edge weights cached in
// registers (CW covers deg<=32; overflow recomputes). BN sum/sq accumulated
// in regs (fixed feature slot f0), LDS-reduced, one atomic set per block.
template <int DOUT>
__global__ void gather_fused(const int* __restrict__ off,
                             const unsigned short* __restrict__ csr,
                             const float* __restrict__ asrc, const float* __restrict__ adst,
                             const unsigned short* __restrict__ hb,
                             const float* __restrict__ b,
                             unsigned short* __restrict__ out,
                             float* __restrict__ bnsum, float* __restrict__ bnsq, int N) {
    constexpr int TPN = DOUT / 8;
    constexpr int CW = 32 / TPN;
    __shared__ float ssum[DOUT];
    __shared__ float ssq[DOUT];
    for (int i = threadIdx.x; i < DOUT; i += BLK) { ssum[i] = 0.f; ssq[i] = 0.f; }
    __syncthreads();

    const int l = threadIdx.x % TPN;              // stride multiple of TPN
    const int f0 = l * 8;
    float4 b0v = *(const float4*)(b + f0);
    float4 b1v = *(const float4*)(b + f0 + 4);
    float bb[8] = {b0v.x, b0v.y, b0v.z, b0v.w, b1v.x, b1v.y, b1v.z, b1v.w};

    long NT = (long)N * TPN;
    long tpt = (long)gridDim.x * blockDim.x;
    float ls[8], lq[8];
#pragma unroll
    for (int i = 0; i < 8; ++i) { ls[i] = 0.f; lq[i] = 0.f; }

    for (long t0 = (long)blockIdx.x * blockDim.x + threadIdx.x; t0 < NT; t0 += tpt) {
        int d = (int)(t0 / TPN);                  // subgroup-uniform (NT % TPN == 0)
        int p0 = off[d], p1 = off[d + 1];
        float ad = adst[d];

        float wreg[CW];
        int sreg[CW];
        float sum = 0.f;
        int idx = 0;
        for (int p = p0 + l; p < p1; p += TPN, ++idx) {
            int s = csr[p];
            float e = asrc[s] + ad;
            e = e > 0.f ? e : 0.2f * e;           // leaky_relu(0.2)
            float w = __expf(e);
            sum += w;
            if (idx < CW) { wreg[idx] = w; sreg[idx] = s; }
        }
#pragma unroll
        for (int o = TPN / 2; o > 0; o >>= 1) sum += __shfl_xor(sum, o, TPN);
        float inv = 1.f / sum;                    // self-loop guarantees sum > 0

        float acc[8];
#pragma unroll
        for (int i = 0; i < 8; ++i) acc[i] = 0.f;

        idx = 0;
        for (int base = p0; base < p1; base += TPN, ++idx) {
            int myp = base + l;
            float w = 0.f;
            int s = 0;
            if (myp < p1) {
                if (idx < CW) { w = wreg[idx] * inv; s = sreg[idx]; }
                else {
                    s = csr[myp];
                    float e = asrc[s] + ad;
                    e = e > 0.f ? e : 0.2f * e;
                    w = __expf(e) * inv;
                }
            }
            int rem = min(TPN, p1 - base);
            for (int j = 0; j < rem; ++j) {
                float aj = __shfl(w, j, TPN);
                int sj = __shfl(s, j, TPN);
                const uint4 hv = *(const uint4*)(hb + (long)sj * DOUT + f0);
                acc[0] += aj * bf2f((unsigned short)(hv.x & 0xffff));
                acc[1] += aj * bf2f((unsigned short)(hv.x >> 16));
                acc[2] += aj * bf2f((unsigned short)(hv.y & 0xffff));
                acc[3] += aj * bf2f((unsigned short)(hv.y >> 16));
                acc[4] += aj * bf2f((unsigned short)(hv.z & 0xffff));
                acc[5] += aj * bf2f((unsigned short)(hv.z >> 16));
                acc[6] += aj * bf2f((unsigned short)(hv.w & 0xffff));
                acc[7] += aj * bf2f((unsigned short)(hv.w >> 16));
            }
        }

        ushort4 o0, o1;
#pragma unroll
        for (int i = 0; i < 8; ++i) {
            float v = acc[i] + bb[i];
            v = v > 0.f ? v : 0.01f * v;          // leaky_relu(0.01)
            ls[i] += v;
            lq[i] += v * v;
            unsigned short hv = f2bf(v);
            if (i < 4) ((unsigned short*)&o0)[i] = hv;
            else       ((unsigned short*)&o1)[i - 4] = hv;
        }
        *(ushort4*)(out + (long)d * DOUT + f0) = o0;
        *(ushort4*)(out + (long)d * DOUT + f0 + 4) = o1;
    }

#pragma unroll
    for (int i = 0; i < 8; ++i) {
        atomicAdd(&ssum[f0 + i], ls[i]);
        atomicAdd(&ssq[f0 + i], lq[i]);
    }
    __syncthreads();
    for (int i = threadIdx.x; i < DOUT; i += BLK) {
        atomicAdd(&bnsum[i], ssum[i]);
        atomicAdd(&bnsq[i], ssq[i]);
    }
}

// ---------------- pool (with inline final BN) + MLP head, fused --------------
__global__ void pool_head_k(const unsigned short* __restrict__ h, const int* __restrict__ gs,
                            const int* __restrict__ ge, const float* __restrict__ bnst,
                            const float* __restrict__ g4, const float* __restrict__ be4,
                            float invN, const float* __restrict__ Wf,
                            const float* __restrict__ bf, const float* __restrict__ Wc,
                            const float* __restrict__ bc, float* __restrict__ out) {
    int g = blockIdx.x;
    int t = threadIdx.x;                          // 64 threads
    __shared__ float p[64];
    __shared__ float z[32];
    float mu = bnst[t] * invN;
    float var = bnst[128 + t] * invN - mu * mu;
    float a = g4[t] * rsqrtf(var + 1e-5f);
    float c = be4[t] - mu * a;
    int s0 = gs[g], s1 = ge[g];
    float acc = 0.f, cnt = 0.f;
    if (s0 <= s1) {
        cnt = (float)(s1 - s0 + 1);
        for (int n = s0; n <= s1; ++n) acc += bf2f(h[(long)n * 64 + t]);
    }
    p[t] = a * acc + cnt * c;
    __syncthreads();
    if (t < 32) {
        float zacc = bf[t];
#pragma unroll
        for (int f = 0; f < 64; ++f) zacc += p[f] * Wf[f * 32 + t];
        z[t] = zacc > 0.f ? zacc : 0.01f * zacc;
    }
    __syncthreads();
    if (t < 8) {
        float oacc = bc[t];
#pragma unroll
        for (int o = 0; o < 32; ++o) oacc += z[o] * Wc[o * 8 + t];
        out[(long)g * 8 + t] = 1.f / (1.f + __expf(-oacc));
    }
}

extern "C" void kernel_launch(void* const* d_in, const int* in_sizes, int n_in,
                              void* d_out, int out_size, void* d_ws, size_t ws_size,
                              hipStream_t stream) {
    const float* x   = (const float*)d_in[0];
    const int* ei    = (const int*)d_in[1];
    const int* batch = (const int*)d_in[2];
    const int N  = in_sizes[2];
    const int E  = in_sizes[1] / 2;
    const int ET = E + N;
    const int G  = out_size / 8;
    const int* src = ei;
    const int* dst = ei + E;

    const float *W[4], *as_[4], *ad_[4], *bb[4], *gg[4], *be_[4];
    for (int i = 0; i < 4; ++i) {
        W[i]   = (const float*)d_in[3 + 6 * i];
        as_[i] = (const float*)d_in[4 + 6 * i];
        ad_[i] = (const float*)d_in[5 + 6 * i];
        bb[i]  = (const float*)d_in[6 + 6 * i];
        gg[i]  = (const float*)d_in[7 + 6 * i];
        be_[i] = (const float*)d_in[8 + 6 * i];
    }
    const float* Wf = (const float*)d_in[27];
    const float* bfp = (const float*)d_in[28];
    const float* Wc = (const float*)d_in[29];
    const float* bc = (const float*)d_in[30];

    float* ws = (float*)d_ws;
    long off_ = 0;
    auto alloc = [&](long nelem) { float* p = ws + off_; off_ += (nelem + 3) & ~3L; return p; };
    unsigned short* h2a = (unsigned short*)alloc((long)N * 64);  // N x 128 bf16
    unsigned short* h2b = (unsigned short*)alloc((long)N * 64);
    unsigned short* hb  = (unsigned short*)alloc((long)N * 64);
    float* asrc     = alloc(N);
    float* adst     = alloc(N);
    float* bnstats  = alloc(4 * 256);       // per-layer: sum[128] | sq[128]
    unsigned* ebkt  = (unsigned*)alloc(E);
    int* histg      = (int*)alloc((long)NBLKA * 256);
    int* bucket_base = (int*)alloc(260);
    int* off        = (int*)alloc(N + 1);
    unsigned short* csr = (unsigned short*)alloc(ET / 2 + 2);
    int* gs         = (int*)alloc(G);
    int* ge         = (int*)alloc(G);
    (void)ws_size; (void)n_in;

    const int nbkt = cdiv(N, 256);          // 196
    const int chunk = cdiv(E, NBLKA);
    const float invN = 1.f / (float)N;

    // ---- CSR build (bucket sort, no global atomics) + graph ranges ----
    histA_k<<<NBLKA, BLK, 0, stream>>>(dst, histg, E, nbkt, chunk);
    bucket_scan_k<<<1, BLK, 0, stream>>>(histg, bucket_base, nbkt, E, gs, ge, G, bnstats);
    blk_scan_k<<<nbkt, BLK, 0, stream>>>(histg, bucket_base, nbkt);
    scatterA_k<<<NBLKA, BLK, 0, stream>>>(src, dst, histg, ebkt, E, nbkt, chunk);
    csrB_k<<<nbkt, BLK, 0, stream>>>(ebkt, bucket_base, off, csr, batch, gs, ge, N, E, nbkt);

#define LAYER(i, DIN, DOUT, AFP32, HASBN, INP, OUTP, BNPREV, GPREV, BEPREV)               \
    do {                                                                                  \
        gemm_fused<DIN, DOUT, AFP32, HASBN>                                               \
            <<<dim3(cdiv(N, 128), DOUT / 16), 256, 0, stream>>>(                          \
                INP, W[i], as_[i], ad_[i], BNPREV, GPREV, BEPREV, invN,                   \
                hb, asrc, adst, N);                                                       \
        int gblk = (int)min((long)GCAP, ((long)N * (DOUT / 8) + BLK - 1) / BLK);          \
        gather_fused<DOUT><<<gblk, BLK, 0, stream>>>(                                     \
            off, csr, asrc, adst, hb, bb[i], OUTP, bnstats + i * 256,                     \
            bnstats + i * 256 + 128, N);                                                  \
    } while (0)

    LAYER(0, 128, 32, true, false, x, h2b, bnstats, gg[0], be_[0]);
    LAYER(1, 32, 64, false, true, h2b, h2a, bnstats + 0 * 256, gg[0], be_[0]);
    LAYER(2, 64, 128, false, true, h2a, h2b, bnstats + 1 * 256, gg[1], be_[1]);
    LAYER(3, 128, 64, false, true, h2b, h2a, bnstats + 2 * 256, gg[2], be_[2]);
#undef LAYER

    pool_head_k<<<G, 64, 0, stream>>>(h2a, gs, ge, bnstats + 3 * 256, gg[3], be_[3],
                                      invN, Wf, bfp, Wc, bc, (float*)d_out);
}

// Round 11
// 387.925 us; speedup vs baseline: 1.2716x; 1.2716x over previous
//
#include <hip/hip_runtime.h>
#include <math.h>

constexpr int BLK = 256;
constexpr int NBLKA = 256;     // phase-A blocks for edge bucketing

static inline int cdiv(long a, long b) { return (int)((a + b - 1) / b); }

typedef __attribute__((ext_vector_type(8))) short short8;
typedef __attribute__((ext_vector_type(4))) float floatx4;

// ---------------- bf16 helpers (RNE) -----------------------------------------
__device__ __forceinline__ unsigned short f2bf(float f) {
    unsigned u = __float_as_uint(f);
    unsigned r = u + 0x7fffu + ((u >> 16) & 1u);
    return (unsigned short)(r >> 16);
}
__device__ __forceinline__ float bf2f(unsigned short s) {
    return __uint_as_float(((unsigned)s) << 16);
}

// ============== CSR build via 2-phase bucket sort (NO global atomics) ========
// Bucket b covers nodes [b*256, b*256+256). histg layout: [z*nbkt + b].

__global__ void histA_k(const int* __restrict__ dst, int* __restrict__ histg,
                        int E, int nbkt, int chunk) {
    __shared__ int h[256];
    int tid = threadIdx.x, z = blockIdx.x;
    h[tid] = 0;
    __syncthreads();
    int e0 = z * chunk, e1 = min(E, e0 + chunk);
    for (int e = e0 + tid; e < e1; e += BLK) atomicAdd(&h[dst[e] >> 8], 1);
    __syncthreads();
    if (tid < nbkt) histg[z * nbkt + tid] = h[tid];
}

__global__ void bucket_scan_k(const int* __restrict__ histg, int* __restrict__ bucket_base,
                              int nbkt, int E, int* __restrict__ gs, int* __restrict__ ge,
                              int G, float* __restrict__ bnstats) {
    __shared__ int s[BLK];
    int t = threadIdx.x;
    int v = 0;
    if (t < nbkt)
        for (int z = 0; z < NBLKA; ++z) v += histg[z * nbkt + t];
    s[t] = v;
    __syncthreads();
    for (int o = 1; o < BLK; o <<= 1) {
        int tv = (t >= o) ? s[t - o] : 0;
        __syncthreads();
        s[t] += tv;
        __syncthreads();
    }
    if (t < nbkt) bucket_base[t] = s[t] - v;
    if (t == 0) bucket_base[nbkt] = E;
    for (int i = t; i < G; i += BLK) { gs[i] = 0x7fffffff; ge[i] = -1; }
    for (int i = t; i < 1024; i += BLK) bnstats[i] = 0.f;   // 4 layers x 256
}

__global__ void blk_scan_k(int* __restrict__ histg, const int* __restrict__ bucket_base,
                           int nbkt) {
    __shared__ int s[BLK];
    int t = threadIdx.x, b = blockIdx.x;
    int v = histg[t * nbkt + b];
    s[t] = v;
    __syncthreads();
    for (int o = 1; o < BLK; o <<= 1) {
        int tv = (t >= o) ? s[t - o] : 0;
        __syncthreads();
        s[t] += tv;
        __syncthreads();
    }
    histg[t * nbkt + b] = bucket_base[b] + s[t] - v;
}

__global__ void scatterA_k(const int* __restrict__ src, const int* __restrict__ dst,
                           const int* __restrict__ histg, unsigned* __restrict__ ebkt,
                           int E, int nbkt, int chunk) {
    __shared__ int cur[256];
    int tid = threadIdx.x, z = blockIdx.x;
    if (tid < nbkt) cur[tid] = histg[z * nbkt + tid];
    __syncthreads();
    int e0 = z * chunk, e1 = min(E, e0 + chunk);
    for (int e = e0 + tid; e < e1; e += BLK) {
        int d = dst[e];
        int b = d >> 8;
        int pos = atomicAdd(&cur[b], 1);
        ebkt[pos] = ((unsigned)(d & 255) << 16) | (unsigned)src[e];
    }
}

// B: per-bucket CSR finalize (degrees->scan->self-loop->fill) + graph ranges.
__global__ void csrB_k(const unsigned* __restrict__ ebkt, const int* __restrict__ bucket_base,
                       int* __restrict__ off, unsigned short* __restrict__ csr,
                       const int* __restrict__ batch, int* __restrict__ gs,
                       int* __restrict__ ge, int N, int E, int nbkt) {
    __shared__ int dg[256];
    __shared__ int sc[256];
    int t = threadIdx.x, b = blockIdx.x;
    int n0 = b << 8;
    int cnt = min(256, N - n0);
    dg[t] = (t < cnt) ? 1 : 0;                     // self-loop
    __syncthreads();
    int e0 = bucket_base[b], e1 = bucket_base[b + 1];
    for (int e = e0 + t; e < e1; e += BLK) atomicAdd(&dg[ebkt[e] >> 16], 1);
    __syncthreads();
    int d = dg[t];
    sc[t] = d;
    __syncthreads();
    for (int o = 1; o < BLK; o <<= 1) {
        int tv = (t >= o) ? sc[t - o] : 0;
        __syncthreads();
        sc[t] += tv;
        __syncthreads();
    }
    int loff = sc[t] - d;                          // exclusive
    int csrbase = e0 + n0;                         // n0 self-loops precede bucket
    if (t < cnt) {
        off[n0 + t] = csrbase + loff;
        csr[csrbase + loff] = (unsigned short)(n0 + t);   // self-loop slot
        dg[t] = loff + 1;                          // cursor
    }
    if (b == nbkt - 1 && t == 0) off[N] = E + N;
    // graph ranges (batch sorted): boundary detection, this grid covers N.
    int n = n0 + t;
    if (n < N) {
        int bb = batch[n];
        if (n == 0) gs[bb] = 0;
        else {
            int pb = batch[n - 1];
            if (pb != bb) { gs[bb] = n; ge[pb] = n - 1; }
        }
        if (n == N - 1) ge[bb] = N - 1;
    }
    __syncthreads();
    for (int e = e0 + t; e < e1; e += BLK) {
        unsigned w = ebkt[e];
        int pos = atomicAdd(&dg[w >> 16], 1);
        csr[csrbase + pos] = (unsigned short)(w & 0xffff);
    }
}

// ---------------- self-contained MFMA GEMM (prep fused in prologue) -----------
template <int K, int NOUT, bool AFP32, bool HASBN>
__launch_bounds__(256)
__global__ void gemm_fused(const void* __restrict__ av, const float* __restrict__ W,
                           const float* __restrict__ a_s, const float* __restrict__ a_d,
                           const float* __restrict__ bnst, const float* __restrict__ g_prev,
                           const float* __restrict__ be_prev, float invN,
                           unsigned short* __restrict__ hb,
                           float* __restrict__ asrc, float* __restrict__ adst, int N) {
    constexpr int KF = K / 32;
    __shared__ float s_sca[K], s_scc[K], s_rs[K], s_rd[K], s_bd[2];
    int tid = threadIdx.x;
    if (tid < K) {
        float a = 1.f, c = 0.f;
        if (HASBN) {
            float mu = bnst[tid] * invN;
            float var = bnst[128 + tid] * invN - mu * mu;
            a = g_prev[tid] * rsqrtf(var + 1e-5f);
            c = be_prev[tid] - mu * a;
        }
        s_sca[tid] = a; s_scc[tid] = c;
    }
    __syncthreads();
    const bool dots = (blockIdx.y == 0);
    if (dots) {                             // block-uniform branch: syncs legal
        if (tid < K) {
            const float* wr = W + (long)tid * NOUT;
            float rs = 0.f, rd = 0.f;
            for (int f = 0; f < NOUT; ++f) {
                float w = wr[f];
                rs += w * a_s[f];
                rd += w * a_d[f];
            }
            s_rs[tid] = rs; s_rd[tid] = rd;
        }
        __syncthreads();
        if (tid < 2) {
            const float* r = tid ? s_rd : s_rs;
            float b = 0.f;
            for (int k = 0; k < K; ++k) b += s_scc[k] * r[k];
            s_bd[tid] = b;
        }
        __syncthreads();
    }

    int wave = tid >> 6;
    int lane = tid & 63;
    int quad = lane >> 4;
    int r16 = lane & 15;
    int col = blockIdx.y * 16 + r16;

    // ---- B fragment (BN-scaled inline) + bias[col] partial ----
    short8 bfr[KF];
    float biasp = 0.f;
#pragma unroll
    for (int kk = 0; kk < KF; ++kk) {
        short8 b;
#pragma unroll
        for (int j = 0; j < 8; ++j) {
            int k = kk * 32 + quad * 8 + j;
            float w = W[(long)k * NOUT + col];
            b[j] = (short)f2bf(s_sca[k] * w);
            biasp += s_scc[k] * w;
        }
        bfr[kk] = b;
    }
    biasp += __shfl_xor(biasp, 16, 64);
    biasp += __shfl_xor(biasp, 32, 64);

    int blockbase = blockIdx.x * 128;
#pragma unroll
    for (int rt = 0; rt < 2; ++rt) {
        int tilebase = blockbase + wave * 32 + rt * 16;
        if (tilebase >= N) break;                       // wave-uniform
        int arow = min(tilebase + r16, N - 1);
        short8 afr[KF];
        if (AFP32) {
            const float* xr = (const float*)av + (long)arow * K;
#pragma unroll
            for (int kk = 0; kk < KF; ++kk) {
                float4 x0 = *(const float4*)(xr + kk * 32 + quad * 8);
                float4 x1 = *(const float4*)(xr + kk * 32 + quad * 8 + 4);
                short8 a;
                a[0] = (short)f2bf(x0.x); a[1] = (short)f2bf(x0.y);
                a[2] = (short)f2bf(x0.z); a[3] = (short)f2bf(x0.w);
                a[4] = (short)f2bf(x1.x); a[5] = (short)f2bf(x1.y);
                a[6] = (short)f2bf(x1.z); a[7] = (short)f2bf(x1.w);
                afr[kk] = a;
            }
        } else {
            const unsigned short* hr = (const unsigned short*)av + (long)arow * K;
#pragma unroll
            for (int kk = 0; kk < KF; ++kk)
                afr[kk] = *(const short8*)(hr + kk * 32 + quad * 8);
        }
        floatx4 acc = {0.f, 0.f, 0.f, 0.f};
#pragma unroll
        for (int kk = 0; kk < KF; ++kk)
            acc = __builtin_amdgcn_mfma_f32_16x16x32_bf16(afr[kk], bfr[kk], acc, 0, 0, 0);
#pragma unroll
        for (int rr = 0; rr < 4; ++rr) {
            int srow = tilebase + quad * 4 + rr;
            if (srow < N) hb[(long)srow * NOUT + col] = f2bf(acc[rr] + biasp);
        }
        if (dots) {
            float ds = 0.f, dd = 0.f;
#pragma unroll
            for (int kk = 0; kk < KF; ++kk) {
                int kb = kk * 32 + quad * 8;
#pragma unroll
                for (int j = 0; j < 8; ++j) {
                    int k = kb + j;
                    float a = bf2f((unsigned short)afr[kk][j]) * s_sca[k];
                    ds += a * s_rs[k];
                    dd += a * s_rd[k];
                }
            }
            ds += __shfl_xor(ds, 16, 64); ds += __shfl_xor(ds, 32, 64);
            dd += __shfl_xor(dd, 16, 64); dd += __shfl_xor(dd, 32, 64);
            int drow = tilebase + r16;
            if (quad == 0 && drow < N) {
                asrc[drow] = ds + s_bd[0];
                adst[drow] = dd + s_bd[1];
            }
        }
    }
}

// ---------------- fused softmax + gather + bias + leaky(0.01), bf16 out ------
// Natural grid (one node per TPN-subgroup). Per-edge weights cached in
// registers (CW covers deg<=32; overflow recomputes). NO stats here —
// fused-stat atomic flush measured slower than a separate 120-block pass.
template <int DOUT>
__global__ void gather_fused(const int* __restrict__ off,
                             const unsigned short* __restrict__ csr,
                             const float* __restrict__ asrc, const float* __restrict__ adst,
                             const unsigned short* __restrict__ hb,
                             const float* __restrict__ b,
                             unsigned short* __restrict__ out, int N) {
    constexpr int TPN = DOUT / 8;
    constexpr int CW = 32 / TPN;
    int t = blockIdx.x * blockDim.x + threadIdx.x;
    int d = t / TPN;
    if (d >= N) return;
    int l = t % TPN;
    int p0 = off[d], p1 = off[d + 1];
    float ad = adst[d];

    float wreg[CW];
    int sreg[CW];
    float sum = 0.f;
    int idx = 0;
    for (int p = p0 + l; p < p1; p += TPN, ++idx) {
        int s = csr[p];
        float e = asrc[s] + ad;
        e = e > 0.f ? e : 0.2f * e;              // leaky_relu(0.2)
        float w = __expf(e);
        sum += w;
        if (idx < CW) { wreg[idx] = w; sreg[idx] = s; }
    }
#pragma unroll
    for (int o = TPN / 2; o > 0; o >>= 1) sum += __shfl_xor(sum, o, TPN);
    float inv = 1.f / sum;                        // self-loop guarantees sum > 0

    float acc[8];
#pragma unroll
    for (int i = 0; i < 8; ++i) acc[i] = 0.f;
    const int f0 = l * 8;

    idx = 0;
    for (int base = p0; base < p1; base += TPN, ++idx) {
        int myp = base + l;
        float w = 0.f;
        int s = 0;
        if (myp < p1) {
            if (idx < CW) { w = wreg[idx] * inv; s = sreg[idx]; }
            else {
                s = csr[myp];
                float e = asrc[s] + ad;
                e = e > 0.f ? e : 0.2f * e;
                w = __expf(e) * inv;
            }
        }
        int rem = min(TPN, p1 - base);
        for (int j = 0; j < rem; ++j) {
            float aj = __shfl(w, j, TPN);
            int sj = __shfl(s, j, TPN);
            const uint4 hv = *(const uint4*)(hb + (long)sj * DOUT + f0);
            acc[0] += aj * bf2f((unsigned short)(hv.x & 0xffff));
            acc[1] += aj * bf2f((unsigned short)(hv.x >> 16));
            acc[2] += aj * bf2f((unsigned short)(hv.y & 0xffff));
            acc[3] += aj * bf2f((unsigned short)(hv.y >> 16));
            acc[4] += aj * bf2f((unsigned short)(hv.z & 0xffff));
            acc[5] += aj * bf2f((unsigned short)(hv.z >> 16));
            acc[6] += aj * bf2f((unsigned short)(hv.w & 0xffff));
            acc[7] += aj * bf2f((unsigned short)(hv.w >> 16));
        }
    }

    float4 b0 = *(const float4*)(b + f0);
    float4 b1 = *(const float4*)(b + f0 + 4);
    float bb[8] = {b0.x, b0.y, b0.z, b0.w, b1.x, b1.y, b1.z, b1.w};
    ushort4 o0, o1;
#pragma unroll
    for (int i = 0; i < 8; ++i) {
        float v = acc[i] + bb[i];
        v = v > 0.f ? v : 0.01f * v;             // leaky_relu(0.01)
        unsigned short hv = f2bf(v);
        if (i < 4) ((unsigned short*)&o0)[i] = hv;
        else       ((unsigned short*)&o1)[i - 4] = hv;
    }
    *(ushort4*)(out + (long)d * DOUT + f0) = o0;
    *(ushort4*)(out + (long)d * DOUT + f0 + 4) = o1;
}

// ---------------- BN statistics over bf16 activations (120-block pass) -------
template <int DOUT>
__global__ void stats_k(const unsigned short* __restrict__ y, float* __restrict__ bnsum,
                        float* __restrict__ bnsq, int N) {
    constexpr int QPR = DOUT / 8;
    __shared__ float ssum[DOUT];
    __shared__ float ssq[DOUT];
    for (int i = threadIdx.x; i < DOUT; i += blockDim.x) { ssum[i] = 0.f; ssq[i] = 0.f; }
    __syncthreads();
    long total = (long)N * QPR;
    long stride = (long)gridDim.x * blockDim.x;     // multiple of QPR
    long t0 = (long)blockIdx.x * blockDim.x + threadIdx.x;
    int f0 = (int)(t0 % QPR) * 8;
    float ls[8], lq[8];
#pragma unroll
    for (int i = 0; i < 8; ++i) { ls[i] = 0.f; lq[i] = 0.f; }
    for (long t = t0; t < total; t += stride) {
        uint4 hv = *(const uint4*)(y + t * 8);
        unsigned vv[4] = {hv.x, hv.y, hv.z, hv.w};
#pragma unroll
        for (int q = 0; q < 4; ++q) {
            float v0 = bf2f((unsigned short)(vv[q] & 0xffff));
            float v1 = bf2f((unsigned short)(vv[q] >> 16));
            ls[2 * q] += v0;     lq[2 * q] += v0 * v0;
            ls[2 * q + 1] += v1; lq[2 * q + 1] += v1 * v1;
        }
    }
#pragma unroll
    for (int i = 0; i < 8; ++i) {
        atomicAdd(&ssum[f0 + i], ls[i]);
        atomicAdd(&ssq[f0 + i], lq[i]);
    }
    __syncthreads();
    for (int i = threadIdx.x; i < DOUT; i += blockDim.x) {
        atomicAdd(&bnsum[i], ssum[i]);
        atomicAdd(&bnsq[i], ssq[i]);
    }
}

// ---------------- pool (with inline final BN) + MLP head, fused --------------
__global__ void pool_head_k(const unsigned short* __restrict__ h, const int* __restrict__ gs,
                            const int* __restrict__ ge, const float* __restrict__ bnst,
                            const float* __restrict__ g4, const float* __restrict__ be4,
                            float invN, const float* __restrict__ Wf,
                            const float* __restrict__ bf, const float* __restrict__ Wc,
                            const float* __restrict__ bc, float* __restrict__ out) {
    int g = blockIdx.x;
    int t = threadIdx.x;                          // 64 threads
    __shared__ float p[64];
    __shared__ float z[32];
    float mu = bnst[t] * invN;
    float var = bnst[128 + t] * invN - mu * mu;
    float a = g4[t] * rsqrtf(var + 1e-5f);
    float c = be4[t] - mu * a;
    int s0 = gs[g], s1 = ge[g];
    float acc = 0.f, cnt = 0.f;
    if (s0 <= s1) {
        cnt = (float)(s1 - s0 + 1);
        for (int n = s0; n <= s1; ++n) acc += bf2f(h[(long)n * 64 + t]);
    }
    p[t] = a * acc + cnt * c;
    __syncthreads();
    if (t < 32) {
        float zacc = bf[t];
#pragma unroll
        for (int f = 0; f < 64; ++f) zacc += p[f] * Wf[f * 32 + t];
        z[t] = zacc > 0.f ? zacc : 0.01f * zacc;
    }
    __syncthreads();
    if (t < 8) {
        float oacc = bc[t];
#pragma unroll
        for (int o = 0; o < 32; ++o) oacc += z[o] * Wc[o * 8 + t];
        out[(long)g * 8 + t] = 1.f / (1.f + __expf(-oacc));
    }
}

extern "C" void kernel_launch(void* const* d_in, const int* in_sizes, int n_in,
                              void* d_out, int out_size, void* d_ws, size_t ws_size,
                              hipStream_t stream) {
    const float* x   = (const float*)d_in[0];
    const int* ei    = (const int*)d_in[1];
    const int* batch = (const int*)d_in[2];
    const int N  = in_sizes[2];
    const int E  = in_sizes[1] / 2;
    const int ET = E + N;
    const int G  = out_size / 8;
    const int* src = ei;
    const int* dst = ei + E;

    const float *W[4], *as_[4], *ad_[4], *bb[4], *gg[4], *be_[4];
    for (int i = 0; i < 4; ++i) {
        W[i]   = (const float*)d_in[3 + 6 * i];
        as_[i] = (const float*)d_in[4 + 6 * i];
        ad_[i] = (const float*)d_in[5 + 6 * i];
        bb[i]  = (const float*)d_in[6 + 6 * i];
        gg[i]  = (const float*)d_in[7 + 6 * i];
        be_[i] = (const float*)d_in[8 + 6 * i];
    }
    const float* Wf = (const float*)d_in[27];
    const float* bfp = (const float*)d_in[28];
    const float* Wc = (const float*)d_in[29];
    const float* bc = (const float*)d_in[30];

    float* ws = (float*)d_ws;
    long off_ = 0;
    auto alloc = [&](long nelem) { float* p = ws + off_; off_ += (nelem + 3) & ~3L; return p; };
    unsigned short* h2a = (unsigned short*)alloc((long)N * 64);  // N x 128 bf16
    unsigned short* h2b = (unsigned short*)alloc((long)N * 64);
    unsigned short* hb  = (unsigned short*)alloc((long)N * 64);
    float* asrc     = alloc(N);
    float* adst     = alloc(N);
    float* bnstats  = alloc(4 * 256);       // per-layer: sum[128] | sq[128]
    unsigned* ebkt  = (unsigned*)alloc(E);
    int* histg      = (int*)alloc((long)NBLKA * 256);
    int* bucket_base = (int*)alloc(260);
    int* off        = (int*)alloc(N + 1);
    unsigned short* csr = (unsigned short*)alloc(ET / 2 + 2);
    int* gs         = (int*)alloc(G);
    int* ge         = (int*)alloc(G);
    (void)ws_size; (void)n_in;

    const int nbkt = cdiv(N, 256);          // 196
    const int chunk = cdiv(E, NBLKA);
    const float invN = 1.f / (float)N;

    // ---- CSR build (bucket sort, no global atomics) + graph ranges ----
    histA_k<<<NBLKA, BLK, 0, stream>>>(dst, histg, E, nbkt, chunk);
    bucket_scan_k<<<1, BLK, 0, stream>>>(histg, bucket_base, nbkt, E, gs, ge, G, bnstats);
    blk_scan_k<<<nbkt, BLK, 0, stream>>>(histg, bucket_base, nbkt);
    scatterA_k<<<NBLKA, BLK, 0, stream>>>(src, dst, histg, ebkt, E, nbkt, chunk);
    csrB_k<<<nbkt, BLK, 0, stream>>>(ebkt, bucket_base, off, csr, batch, gs, ge, N, E, nbkt);

#define LAYER(i, DIN, DOUT, AFP32, HASBN, INP, OUTP, BNPREV, GPREV, BEPREV)               \
    do {                                                                                  \
        gemm_fused<DIN, DOUT, AFP32, HASBN>                                               \
            <<<dim3(cdiv(N, 128), DOUT / 16), 256, 0, stream>>>(                          \
                INP, W[i], as_[i], ad_[i], BNPREV, GPREV, BEPREV, invN,                   \
                hb, asrc, adst, N);                                                       \
        gather_fused<DOUT><<<cdiv((long)N * (DOUT / 8), BLK), BLK, 0, stream>>>(          \
            off, csr, asrc, adst, hb, bb[i], OUTP, N);                                    \
        stats_k<DOUT><<<120, BLK, 0, stream>>>(OUTP, bnstats + i * 256,                   \
                                               bnstats + i * 256 + 128, N);               \
    } while (0)

    LAYER(0, 128, 32, true, false, x, h2b, bnstats, gg[0], be_[0]);
    LAYER(1, 32, 64, false, true, h2b, h2a, bnstats + 0 * 256, gg[0], be_[0]);
    LAYER(2, 64, 128, false, true, h2a, h2b, bnstats + 1 * 256, gg[1], be_[1]);
    LAYER(3, 128, 64, false, true, h2b, h2a, bnstats + 2 * 256, gg[2], be_[2]);
#undef LAYER

    pool_head_k<<<G, 64, 0, stream>>>(h2a, gs, ge, bnstats + 3 * 256, gg[3], be_[3],
                                      invN, Wf, bfp, Wc, bc, (float*)d_out);
}